// Round 1
// baseline (261.934 us; speedup 1.0000x reference)
//
#include <hip/hip_runtime.h>

// Problem constants (match setup_inputs in the reference)
#define B_   16
#define R_   16
#define T_   4
#define S_   14
#define NPRB 273
#define NPD  6      // pilots per DMRS symbol per PRB (subcarrier positions)
#define NDS  2      // number of DMRS OFDM symbols
#define RE_  12     // resource elements per PRB
#define P_   (NDS*NPRB*NPD)   // 3276 pilots total
#define NSC  (NPRB*RE_)       // 3276 subcarriers
#define F_   (RE_*S_)         // 168 grid positions per tx

#define NH   (B_*T_*NSC*S_*R_)   // 46964736 floats (h_full)
#define NPE  (T_*NSC*S_*2)       // 366912 floats (pe)
#define NH4  (NH/4)
#define NPE4 (NPE/4)
#define NTOT4 (NH4+NPE4)

// Kernel A: tiny one-block kernel. Computes, per tx and per flat grid index f
// (where f was laid out as re-major: re = f/14, s = f%14 — reproducing the
// reference's reshape quirk):
//   qtab[t][f]   = ds*NPRB*NPD + (sc & ~1)   (even FOCC-pair base, minus prb*NPD term)
//   pe_base[t][f][0] = normalized min time-distance   (channels swapped as in ref)
//   pe_base[t][f][1] = normalized min freq-distance
__global__ void prep_tables(const int* __restrict__ ofdm_pos,     // [T_,NDS]
                            const int* __restrict__ sc_pos,       // [T_,NPD]
                            int* __restrict__ qtab,               // [T_*F_]
                            float* __restrict__ pe_base)          // [T_*F_*2]
{
    __shared__ float dt_sh[T_*F_];
    __shared__ float df_sh[T_*F_];
    __shared__ float stats[T_][4]; // mean_t, inv_std_t, mean_f, inv_std_f
    const int tid = threadIdx.x;
    if (tid < T_*F_) {
        const int t = tid / F_, f = tid % F_;
        const int re = f / S_, s = f % S_;   // reference's re-major flat layout
        int best = 1 << 30, bestj = 0;
        int dfmin = 1 << 30, dtmin = 1 << 30;
        for (int sci = 0; sci < NPD; ++sci) {
            const int dsc = abs(re - sc_pos[t*NPD + sci]);
            if (dsc < dfmin) dfmin = dsc;
            for (int ofi = 0; ofi < NDS; ++ofi) {
                const int dof = abs(s - ofdm_pos[t*NDS + ofi]);
                const int d = dsc + dof;
                // j = sci*NDS + ofi increases monotonically; strict < keeps the
                // FIRST minimum, matching jnp.argmin tie-breaking.
                if (d < best) { best = d; bestj = sci*NDS + ofi; }
            }
        }
        for (int ofi = 0; ofi < NDS; ++ofi) {
            const int dof = abs(s - ofdm_pos[t*NDS + ofi]);
            if (dof < dtmin) dtmin = dof;
        }
        const int sc = bestj / NDS, ds = bestj % NDS;
        const int sc0 = sc & ~1;            // FOCC pair: even member
        qtab[tid] = ds*(NPRB*NPD) + sc0;
        dt_sh[tid] = (float)dtmin;
        df_sh[tid] = (float)dfmin;
    }
    __syncthreads();
    if (tid < T_*F_ && (tid % F_) == 0) {
        const int t = tid / F_;
        float s1t = 0.f, s1f = 0.f;
        for (int i = 0; i < F_; ++i) { s1t += dt_sh[t*F_+i]; s1f += df_sh[t*F_+i]; }
        const float mt = s1t / (float)F_, mf = s1f / (float)F_;
        float vt = 0.f, vf = 0.f;
        for (int i = 0; i < F_; ++i) {
            const float a = dt_sh[t*F_+i] - mt; vt += a*a;
            const float b = df_sh[t*F_+i] - mf; vf += b*b;
        }
        const float stdt = sqrtf(vt / (float)(F_-1));  // ddof=1 (torch .std())
        const float stdf = sqrtf(vf / (float)(F_-1));
        stats[t][0] = mt; stats[t][1] = 1.0f/(stdt + 1e-8f);
        stats[t][2] = mf; stats[t][3] = 1.0f/(stdf + 1e-8f);
    }
    __syncthreads();
    if (tid < T_*F_) {
        const int t = tid / F_;
        // channel order swapped exactly as in the reference: [time, freq]
        pe_base[tid*2 + 0] = (dt_sh[tid] - stats[t][0]) * stats[t][1];
        pe_base[tid*2 + 1] = (df_sh[tid] - stats[t][2]) * stats[t][3];
    }
}

// Kernel B: one thread per output float4. First NH4 threads write h_full,
// remainder write pe. h path: fully coalesced float4 store, two cached float4
// loads (FOCC pair) + average.
__global__ __launch_bounds__(256) void gather_kernel(
    const float* __restrict__ hls,     // h_hat_ls [B_, P_, T_, R_]
    const int* __restrict__ qtab,      // [T_*F_]
    const float* __restrict__ pe_base, // [T_*F_*2]
    float* __restrict__ out)           // h_full (NH) then pe (NPE)
{
    const int idx = blockIdx.x * blockDim.x + threadIdx.x;
    if (idx >= NTOT4) return;
    if (idx < NH4) {
        // h_full flat float index = (((b*T_ + t)*NSC + k)*S_ + s)*R_ + r
        const int r4 = idx & 3;
        int u = idx >> 2;
        const int s = u % S_;  u /= S_;
        const int k = u % NSC; u /= NSC;
        const int t = u & (T_-1);
        const int b = u >> 2;
        const int prb = k / RE_;
        const int re  = k - prb*RE_;
        // reference's scrambled lookup: flat table index f = s*RE + re
        const int f  = s*RE_ + re;
        const int p0 = qtab[t*F_ + f] + prb*NPD;   // even pilot of the FOCC pair
        const float4* src = (const float4*)hls + ((b*P_ + p0)*T_ + t)*(R_/4) + r4;
        const float4 a = src[0];
        const float4 c = src[T_*(R_/4)];           // pilot p0+1: +T_*R_ floats
        float4 o;
        o.x = 0.5f*(a.x + c.x);
        o.y = 0.5f*(a.y + c.y);
        o.z = 0.5f*(a.z + c.z);
        o.w = 0.5f*(a.w + c.w);
        ((float4*)out)[idx] = o;
    } else {
        // pe flat float index = ((t*NSC + i)*S_ + s)*2 + c ; value depends on
        // (t, i%RE_, s, c) only.
        const int g0 = (idx - NH4) * 4;
        float v[4];
        #pragma unroll
        for (int u2 = 0; u2 < 4; ++u2) {
            const int g  = g0 + u2;
            const int c  = g & 1;
            const int g1 = g >> 1;
            const int s  = g1 % S_;
            const int g2 = g1 / S_;
            const int i  = g2 % NSC;
            const int t  = g2 / NSC;
            const int re = i % RE_;
            v[u2] = pe_base[(t*F_ + s*RE_ + re)*2 + c];
        }
        float4 o; o.x = v[0]; o.y = v[1]; o.z = v[2]; o.w = v[3];
        ((float4*)(out + NH))[idx - NH4] = o;
    }
}

extern "C" void kernel_launch(void* const* d_in, const int* in_sizes, int n_in,
                              void* d_out, int out_size, void* d_ws, size_t ws_size,
                              hipStream_t stream) {
    // inputs: y (unused, shape only), h_hat_ls f32, dmrs_ofdm_pos i32, dmrs_subcarrier_pos i32
    const float* hls  = (const float*)d_in[1];
    const int*   ofdm = (const int*)d_in[2];
    const int*   scp  = (const int*)d_in[3];
    float* out = (float*)d_out;

    int*   qtab    = (int*)d_ws;
    float* pe_base = (float*)((char*)d_ws + T_*F_*sizeof(int));

    hipLaunchKernelGGL(prep_tables, dim3(1), dim3(T_*F_), 0, stream,
                       ofdm, scp, qtab, pe_base);

    const int blocks = (NTOT4 + 255) / 256;
    hipLaunchKernelGGL(gather_kernel, dim3(blocks), dim3(256), 0, stream,
                       hls, qtab, pe_base, out);
}